// Round 4
// baseline (5814.104 us; speedup 1.0000x reference)
//
#include <hip/hip_runtime.h>

// hd_id_lvl_decoder: scores[b,i,l] = sum_d x[b,d]*id[i,d]*lvl[l,d]; out[b,i] = argmax_l * 0.015625
// B=64, NUM_ID=256, NUM_LVL=64, D=10000. fp32 vector ALU (no fp32 MFMA on CDNA4).
//
// Phase 1: K-split GEMM-like kernel. Block tile = 64 i x 64 l x 8 b, thread tile = 8x4x4 (128 acc).
//          Grid = 32 * S blocks (S = K-splits; S=32 -> 1024 blocks = 4/CU at 128 VGPR / 88 KB LDS).
// Phase 2: one wave per (b,i), lane = l: fp64 sum of S partials, shfl_xor argmax (first-index ties).

constexpr int D  = 10000;
constexpr int B  = 64;
constexpr int NI = 256;
constexpr int NL = 64;
constexpr int KC = 20;                 // k per chunk
constexpr int TOTAL_CH = D / KC;       // 500 chunks total
constexpr float BIN_LEN = 0.015625f;

constexpr int TI = 64;                 // i per block
constexpr int TB = 8;                  // b per block
constexpr int UNITS = (64 + 64 + 8) * (KC / 4);  // 680 float4 staging units per chunk

__device__ __forceinline__ float4 ld4(const float* p) {
    return *reinterpret_cast<const float4*>(p);
}

struct Pre { float4 v[3]; };

__device__ __forceinline__ void stage_load(Pre& r, const float* __restrict__ id_hvs,
                                           const float* __restrict__ lvl_hvs,
                                           const float* __restrict__ x,
                                           int kk, int ibase, int bbase, int tid) {
#pragma unroll
    for (int m = 0; m < 3; ++m) {
        int u = tid + 256 * m;
        if (u < UNITS) {
            const float* src;
            if (u < 320) {                   // id tile: 64 cols x 5 kgroups
                int col = u & 63, g = u >> 6;
                src = id_hvs + (size_t)(ibase + col) * D + kk + 4 * g;
            } else if (u < 640) {            // lvl tile
                int u2 = u - 320;
                int col = u2 & 63, g = u2 >> 6;
                src = lvl_hvs + (size_t)col * D + kk + 4 * g;
            } else {                         // x tile: 8 cols x 5 kgroups
                int u3 = u - 640;
                int col = u3 & 7, g = u3 >> 3;
                src = x + (size_t)(bbase + col) * D + kk + 4 * g;
            }
            r.v[m] = ld4(src);
        }
    }
}

__device__ __forceinline__ void stage_write(float (*pid)[64], float (*plvl)[64],
                                            float (*px)[8], const Pre& r, int tid) {
#pragma unroll
    for (int m = 0; m < 3; ++m) {
        int u = tid + 256 * m;
        if (u < UNITS) {
            float vv[4] = {r.v[m].x, r.v[m].y, r.v[m].z, r.v[m].w};
            if (u < 320) {
                int col = u & 63, g = u >> 6;
#pragma unroll
                for (int j = 0; j < 4; ++j) pid[4 * g + j][col] = vv[j];
            } else if (u < 640) {
                int u2 = u - 320;
                int col = u2 & 63, g = u2 >> 6;
#pragma unroll
                for (int j = 0; j < 4; ++j) plvl[4 * g + j][col] = vv[j];
            } else {
                int u3 = u - 640;
                int col = u3 & 7, g = u3 >> 3;
#pragma unroll
                for (int j = 0; j < 4; ++j) px[4 * g + j][col] = vv[j];
            }
        }
    }
}

__global__ __launch_bounds__(256, 4)
void hd_phase1(const float* __restrict__ x, const float* __restrict__ id_hvs,
               const float* __restrict__ lvl_hvs, float* __restrict__ ws, int S) {
    __shared__ float sid[2][KC][64];
    __shared__ float slvl[2][KC][64];
    __shared__ float sx[2][KC][8];

    const int tid = threadIdx.x;
    const int bx  = blockIdx.x;
    const int s    = bx >> 5;         // split index (32 blocks per split)
    const int bblk = (bx >> 2) & 7;   // 8 b-blocks
    const int iblk = bx & 3;          // 4 i-blocks
    const int ibase = iblk * TI;
    const int bbase = bblk * TB;

    const int lcol = (tid & 15) * 4;        // Q=4 l's
    const int icol = ((tid >> 4) & 7) * 8;  // P=8 i's
    const int bcol = (tid >> 7) * 4;        // R=4 b's

    // split k-range (all multiples of KC -> 16B-aligned global float4 loads)
    const int cbase = TOTAL_CH / S, crem = TOTAL_CH % S;
    const int cstart = s * cbase + (s < crem ? s : crem);
    const int nch    = cbase + (s < crem ? 1 : 0);
    const int k0     = cstart * KC;

    float acc[4][8][4];  // [r=b][p=i][q=l]
#pragma unroll
    for (int r = 0; r < 4; ++r)
#pragma unroll
        for (int p = 0; p < 8; ++p)
#pragma unroll
            for (int q = 0; q < 4; ++q) acc[r][p][q] = 0.0f;

    Pre pre;
    stage_load(pre, id_hvs, lvl_hvs, x, k0, ibase, bbase, tid);
    stage_write(sid[0], slvl[0], sx[0], pre, tid);
    __syncthreads();

    int cur = 0;
    for (int c = 0; c < nch; ++c) {
        const bool more = (c + 1 < nch);
        if (more) stage_load(pre, id_hvs, lvl_hvs, x, k0 + (c + 1) * KC, ibase, bbase, tid);

        const float (*pid)[64] = sid[cur];
        const float (*plvl)[64] = slvl[cur];
        const float (*px)[8] = sx[cur];

#pragma unroll 5
        for (int k = 0; k < KC; ++k) {
            const float4 A0 = ld4(&pid[k][icol]);
            const float4 A1 = ld4(&pid[k][icol + 4]);
            const float4 LV = ld4(&plvl[k][lcol]);
            const float4 XV = ld4(&px[k][bcol]);
            const float a[8]  = {A0.x, A0.y, A0.z, A0.w, A1.x, A1.y, A1.z, A1.w};
            const float lq[4] = {LV.x, LV.y, LV.z, LV.w};
            const float xr[4] = {XV.x, XV.y, XV.z, XV.w};
            float w[4][4];
#pragma unroll
            for (int r = 0; r < 4; ++r)
#pragma unroll
                for (int q = 0; q < 4; ++q) w[r][q] = xr[r] * lq[q];
#pragma unroll
            for (int r = 0; r < 4; ++r)
#pragma unroll
                for (int p = 0; p < 8; ++p)
#pragma unroll
                    for (int q = 0; q < 4; ++q)
                        acc[r][p][q] = fmaf(a[p], w[r][q], acc[r][p][q]);
        }

        if (more) stage_write(sid[cur ^ 1], slvl[cur ^ 1], sx[cur ^ 1], pre, tid);
        __syncthreads();
        cur ^= 1;
    }

    // store partials: ws[((s*64 + b)*256 + i)*64 + l]
#pragma unroll
    for (int r = 0; r < 4; ++r) {
#pragma unroll
        for (int p = 0; p < 8; ++p) {
            float4 o;
            o.x = acc[r][p][0]; o.y = acc[r][p][1]; o.z = acc[r][p][2]; o.w = acc[r][p][3];
            size_t idx = (((size_t)(s * B + bbase + bcol + r)) * NI + (ibase + icol + p)) * NL + lcol;
            *reinterpret_cast<float4*>(ws + idx) = o;
        }
    }
}

// One wave per (b,i); lane = l. Coalesced 256B reads per split, fp64 reduce, butterfly argmax.
__global__ __launch_bounds__(256)
void hd_phase2(const float* __restrict__ ws, float* __restrict__ out, int S) {
    const int wid  = blockIdx.x * 4 + (threadIdx.x >> 6);   // (b,i) flat index, 0..16383
    const int lane = threadIdx.x & 63;                       // l
    const int b = wid >> 8, i = wid & 255;
    const float* p = ws + ((size_t)b * NI + i) * NL + lane;
    const size_t sstride = (size_t)B * NI * NL;              // 1,048,576 floats per split

    double s0 = 0.0, s1 = 0.0, s2 = 0.0, s3 = 0.0;
    int ss = 0;
    for (; ss + 4 <= S; ss += 4) {
        s0 += (double)p[(size_t)(ss + 0) * sstride];
        s1 += (double)p[(size_t)(ss + 1) * sstride];
        s2 += (double)p[(size_t)(ss + 2) * sstride];
        s3 += (double)p[(size_t)(ss + 3) * sstride];
    }
    for (; ss < S; ++ss) s0 += (double)p[(size_t)ss * sstride];

    double mv = (s0 + s1) + (s2 + s3);
    int mi = lane;
#pragma unroll
    for (int off = 1; off < 64; off <<= 1) {
        double ov = __shfl_xor(mv, off);
        int   oi  = __shfl_xor(mi, off);
        if (ov > mv || (ov == mv && oi < mi)) { mv = ov; mi = oi; }  // first-index tie-break
    }
    if (lane == 0) out[wid] = (float)mi * BIN_LEN;
}

extern "C" void kernel_launch(void* const* d_in, const int* in_sizes, int n_in,
                              void* d_out, int out_size, void* d_ws, size_t ws_size,
                              hipStream_t stream) {
    const float* x       = (const float*)d_in[0];
    const float* id_hvs  = (const float*)d_in[1];
    const float* lvl_hvs = (const float*)d_in[2];
    float* out = (float*)d_out;
    float* ws  = (float*)d_ws;

    // pick largest split count whose partial buffer (S * 4 MiB) fits in ws
    int S = 32;
    while (S > 1 && ws_size < ((size_t)S << 22)) S >>= 1;

    hd_phase1<<<dim3(32 * S), dim3(256), 0, stream>>>(x, id_hvs, lvl_hvs, ws, S);
    // one wave per (b,i): 16384 waves = 4096 blocks of 4 waves
    hd_phase2<<<dim3(B * NI / 4), dim3(256), 0, stream>>>(ws, out, S);
}

// Round 5
// 259.704 us; speedup vs baseline: 22.3875x; 22.3875x over previous
//
#include <hip/hip_runtime.h>

// hd_id_lvl_decoder: scores[b,i,l] = sum_d x[b,d]*id[i,d]*lvl[l,d]; out[b,i] = argmax_l * 0.015625
// B=64, NUM_ID=256, NUM_LVL=64, D=10000. fp32 vector ALU (no fp32 MFMA on CDNA4).
//
// Phase 1: K-split GEMM-like kernel. Block tile = 64 i x 64 l x 8 b, thread tile = 8x4x4 (128 acc).
//          Grid = 32 * S blocks (S=32 -> 1024 blocks = 4/CU). __launch_bounds__(256,2): bound (256,4)
//          squeezed VGPRs to 64 and spilled the 128-reg acc tile to scratch (31 GB traffic, R4).
//          With (256,2) the compiler allocates 128 VGPR (R2-verified) and HW still fits 4 blocks/CU.
// Phase 2: one wave per (b,i), lane = l: fp64 sum of S partials, shfl_xor argmax (first-index ties).

constexpr int D  = 10000;
constexpr int B  = 64;
constexpr int NI = 256;
constexpr int NL = 64;
constexpr int KC = 20;                 // k per chunk
constexpr int TOTAL_CH = D / KC;       // 500 chunks total
constexpr float BIN_LEN = 0.015625f;

constexpr int TI = 64;                 // i per block
constexpr int TB = 8;                  // b per block
constexpr int UNITS = (64 + 64 + 8) * (KC / 4);  // 680 float4 staging units per chunk

__device__ __forceinline__ float4 ld4(const float* p) {
    return *reinterpret_cast<const float4*>(p);
}

struct Pre { float4 v[3]; };

__device__ __forceinline__ void stage_load(Pre& r, const float* __restrict__ id_hvs,
                                           const float* __restrict__ lvl_hvs,
                                           const float* __restrict__ x,
                                           int kk, int ibase, int bbase, int tid) {
#pragma unroll
    for (int m = 0; m < 3; ++m) {
        int u = tid + 256 * m;
        if (u < UNITS) {
            const float* src;
            if (u < 320) {                   // id tile: 64 cols x 5 kgroups
                int col = u & 63, g = u >> 6;
                src = id_hvs + (size_t)(ibase + col) * D + kk + 4 * g;
            } else if (u < 640) {            // lvl tile
                int u2 = u - 320;
                int col = u2 & 63, g = u2 >> 6;
                src = lvl_hvs + (size_t)col * D + kk + 4 * g;
            } else {                         // x tile: 8 cols x 5 kgroups
                int u3 = u - 640;
                int col = u3 & 7, g = u3 >> 3;
                src = x + (size_t)(bbase + col) * D + kk + 4 * g;
            }
            r.v[m] = ld4(src);
        }
    }
}

__device__ __forceinline__ void stage_write(float (*pid)[64], float (*plvl)[64],
                                            float (*px)[8], const Pre& r, int tid) {
#pragma unroll
    for (int m = 0; m < 3; ++m) {
        int u = tid + 256 * m;
        if (u < UNITS) {
            float vv[4] = {r.v[m].x, r.v[m].y, r.v[m].z, r.v[m].w};
            if (u < 320) {
                int col = u & 63, g = u >> 6;
#pragma unroll
                for (int j = 0; j < 4; ++j) pid[4 * g + j][col] = vv[j];
            } else if (u < 640) {
                int u2 = u - 320;
                int col = u2 & 63, g = u2 >> 6;
#pragma unroll
                for (int j = 0; j < 4; ++j) plvl[4 * g + j][col] = vv[j];
            } else {
                int u3 = u - 640;
                int col = u3 & 7, g = u3 >> 3;
#pragma unroll
                for (int j = 0; j < 4; ++j) px[4 * g + j][col] = vv[j];
            }
        }
    }
}

__global__ __launch_bounds__(256, 2)
void hd_phase1(const float* __restrict__ x, const float* __restrict__ id_hvs,
               const float* __restrict__ lvl_hvs, float* __restrict__ ws, int S) {
    __shared__ float sid[2][KC][64];
    __shared__ float slvl[2][KC][64];
    __shared__ float sx[2][KC][8];

    const int tid = threadIdx.x;
    const int bx  = blockIdx.x;
    const int s    = bx >> 5;         // split index (32 blocks per split)
    const int bblk = (bx >> 2) & 7;   // 8 b-blocks
    const int iblk = bx & 3;          // 4 i-blocks
    const int ibase = iblk * TI;
    const int bbase = bblk * TB;

    const int lcol = (tid & 15) * 4;        // Q=4 l's
    const int icol = ((tid >> 4) & 7) * 8;  // P=8 i's
    const int bcol = (tid >> 7) * 4;        // R=4 b's

    // split k-range (all multiples of KC -> 16B-aligned global float4 loads)
    const int cbase = TOTAL_CH / S, crem = TOTAL_CH % S;
    const int cstart = s * cbase + (s < crem ? s : crem);
    const int nch    = cbase + (s < crem ? 1 : 0);
    const int k0     = cstart * KC;

    float acc[4][8][4];  // [r=b][p=i][q=l]
#pragma unroll
    for (int r = 0; r < 4; ++r)
#pragma unroll
        for (int p = 0; p < 8; ++p)
#pragma unroll
            for (int q = 0; q < 4; ++q) acc[r][p][q] = 0.0f;

    Pre pre;
    stage_load(pre, id_hvs, lvl_hvs, x, k0, ibase, bbase, tid);
    stage_write(sid[0], slvl[0], sx[0], pre, tid);
    __syncthreads();

    int cur = 0;
    for (int c = 0; c < nch; ++c) {
        const bool more = (c + 1 < nch);
        if (more) stage_load(pre, id_hvs, lvl_hvs, x, k0 + (c + 1) * KC, ibase, bbase, tid);

        const float (*pid)[64] = sid[cur];
        const float (*plvl)[64] = slvl[cur];
        const float (*px)[8] = sx[cur];

#pragma unroll 5
        for (int k = 0; k < KC; ++k) {
            const float4 A0 = ld4(&pid[k][icol]);
            const float4 A1 = ld4(&pid[k][icol + 4]);
            const float4 LV = ld4(&plvl[k][lcol]);
            const float4 XV = ld4(&px[k][bcol]);
            const float a[8]  = {A0.x, A0.y, A0.z, A0.w, A1.x, A1.y, A1.z, A1.w};
            const float lq[4] = {LV.x, LV.y, LV.z, LV.w};
            const float xr[4] = {XV.x, XV.y, XV.z, XV.w};
            float w[4][4];
#pragma unroll
            for (int r = 0; r < 4; ++r)
#pragma unroll
                for (int q = 0; q < 4; ++q) w[r][q] = xr[r] * lq[q];
#pragma unroll
            for (int r = 0; r < 4; ++r)
#pragma unroll
                for (int p = 0; p < 8; ++p)
#pragma unroll
                    for (int q = 0; q < 4; ++q)
                        acc[r][p][q] = fmaf(a[p], w[r][q], acc[r][p][q]);
        }

        if (more) stage_write(sid[cur ^ 1], slvl[cur ^ 1], sx[cur ^ 1], pre, tid);
        __syncthreads();
        cur ^= 1;
    }

    // store partials: ws[((s*64 + b)*256 + i)*64 + l]
#pragma unroll
    for (int r = 0; r < 4; ++r) {
#pragma unroll
        for (int p = 0; p < 8; ++p) {
            float4 o;
            o.x = acc[r][p][0]; o.y = acc[r][p][1]; o.z = acc[r][p][2]; o.w = acc[r][p][3];
            size_t idx = (((size_t)(s * B + bbase + bcol + r)) * NI + (ibase + icol + p)) * NL + lcol;
            *reinterpret_cast<float4*>(ws + idx) = o;
        }
    }
}

// One wave per (b,i); lane = l. Coalesced 256B reads per split, fp64 reduce, butterfly argmax.
__global__ __launch_bounds__(256)
void hd_phase2(const float* __restrict__ ws, float* __restrict__ out, int S) {
    const int wid  = blockIdx.x * 4 + (threadIdx.x >> 6);   // (b,i) flat index, 0..16383
    const int lane = threadIdx.x & 63;                       // l
    const int b = wid >> 8, i = wid & 255;
    const float* p = ws + ((size_t)b * NI + i) * NL + lane;
    const size_t sstride = (size_t)B * NI * NL;              // 1,048,576 floats per split

    double s0 = 0.0, s1 = 0.0, s2 = 0.0, s3 = 0.0;
    int ss = 0;
    for (; ss + 4 <= S; ss += 4) {
        s0 += (double)p[(size_t)(ss + 0) * sstride];
        s1 += (double)p[(size_t)(ss + 1) * sstride];
        s2 += (double)p[(size_t)(ss + 2) * sstride];
        s3 += (double)p[(size_t)(ss + 3) * sstride];
    }
    for (; ss < S; ++ss) s0 += (double)p[(size_t)ss * sstride];

    double mv = (s0 + s1) + (s2 + s3);
    int mi = lane;
#pragma unroll
    for (int off = 1; off < 64; off <<= 1) {
        double ov = __shfl_xor(mv, off);
        int   oi  = __shfl_xor(mi, off);
        if (ov > mv || (ov == mv && oi < mi)) { mv = ov; mi = oi; }  // first-index tie-break
    }
    if (lane == 0) out[wid] = (float)mi * BIN_LEN;
}

extern "C" void kernel_launch(void* const* d_in, const int* in_sizes, int n_in,
                              void* d_out, int out_size, void* d_ws, size_t ws_size,
                              hipStream_t stream) {
    const float* x       = (const float*)d_in[0];
    const float* id_hvs  = (const float*)d_in[1];
    const float* lvl_hvs = (const float*)d_in[2];
    float* out = (float*)d_out;
    float* ws  = (float*)d_ws;

    // pick largest split count whose partial buffer (S * 4 MiB) fits in ws
    int S = 32;
    while (S > 1 && ws_size < ((size_t)S << 22)) S >>= 1;

    hd_phase1<<<dim3(32 * S), dim3(256), 0, stream>>>(x, id_hvs, lvl_hvs, ws, S);
    // one wave per (b,i): 16384 waves = 4096 blocks of 4 waves
    hd_phase2<<<dim3(B * NI / 4), dim3(256), 0, stream>>>(ws, out, S);
}

// Round 6
// 127.930 us; speedup vs baseline: 45.4477x; 2.0301x over previous
//
#include <hip/hip_runtime.h>

// hd_id_lvl_decoder: scores[b,i,l] = sum_d x[b,d]*id[i,d]*lvl[l,d]; out[b,i] = argmax_l * 0.015625
// B=64, NUM_ID=256, NUM_LVL=64, D=10000.
//
// f16x2-split MFMA version: a = hi + lo (f16 pair, residual ~2^-23|a|);
// a*b = hh + hl + lh + ll via 4x mfma_f32_16x16x32_f16 -> fp32-accurate products at f16 MFMA rate.
// Phase 0: split id_hvs into f16 hi/lo arrays (zero-padded K to 10016 = 313*32) in ws.
// Phase 1: per block (b, i-tile of 128, k-split s): fold w = x[b]*lvl in fp32, split to f16 in-reg,
//          stage swizzled LDS, MFMA into 2 accs (main hh + correction). Partials to ws.
// Phase 2: one wave per (b,i), lane = l: fp64 sum of S partials, shfl_xor argmax (first-index ties).

typedef _Float16 f16x8 __attribute__((ext_vector_type(8)));
typedef float f32x4 __attribute__((ext_vector_type(4)));

constexpr int D    = 10000;
constexpr int KPAD = 10016;            // 313 * 32
constexpr int B    = 64;
constexpr int NI   = 256;
constexpr int NL   = 64;
constexpr int BK   = 32;
constexpr int NCH  = KPAD / BK;        // 313 chunks
constexpr int S    = 8;                // k-splits
constexpr int BM   = 128;              // i per block
constexpr float BIN_LEN = 0.015625f;

// ws layout (bytes): [0, 32M) partials; then idh (256*10016 f16), idl.
constexpr size_t OFF_IDH = (size_t)S * B * NI * NL * 4;          // 33,554,432
constexpr size_t IDSZ    = (size_t)NI * KPAD;                     // elements per id array

__device__ __forceinline__ float4 ld4(const float* p) {
    return *reinterpret_cast<const float4*>(p);
}

// ---------------- Phase 0: split id into f16 hi/lo, zero-pad to KPAD ----------------
__global__ __launch_bounds__(256)
void hd_split_id(const float* __restrict__ id_hvs,
                 _Float16* __restrict__ idh, _Float16* __restrict__ idl) {
    const int i = blockIdx.x;          // 256 blocks, one i-row each
    for (int k = threadIdx.x; k < KPAD; k += 256) {
        float v = (k < D) ? id_hvs[(size_t)i * D + k] : 0.0f;
        _Float16 h = (_Float16)v;
        _Float16 lo = (_Float16)(v - (float)h);
        idh[(size_t)i * KPAD + k] = h;
        idl[(size_t)i * KPAD + k] = lo;
    }
}

// ---------------- Phase 1: MFMA main kernel ----------------
__global__ __launch_bounds__(256)
void hd_mfma(const float* __restrict__ x, const float* __restrict__ lvl_hvs,
             const _Float16* __restrict__ idh, const _Float16* __restrict__ idl,
             float* __restrict__ part) {
    // [buf][hi/lo][row][slot] ; slot = kg ^ ((row>>1)&3) swizzle -> <=2-way banks on r/w
    __shared__ f16x8 sA[2][2][BM][4];   // id tiles, 32 KB
    __shared__ f16x8 sW[2][2][NL][4];   // w = x*lvl tiles, 16 KB

    const int tid = threadIdx.x;
    const int bx  = blockIdx.x;
    const int s     = bx >> 7;          // 0..S-1
    const int rem   = bx & 127;
    const int b     = rem >> 1;         // 0..63
    const int ibase = (rem & 1) * BM;   // 0 or 128

    // chunk range for this split
    const int cb = NCH / S, cr = NCH % S;          // 39, 1
    const int cstart = s * cb + (s < cr ? s : cr);
    const int nch    = cb + (s < cr ? 1 : 0);

    // staging assignments
    // id: 4 units/thread: u = tid+256m -> arr=u>>9, row=(u&511)>>2, kg=u&3 (kg-fast: 64B coalesced)
    // w : 1 unit/thread: lrow = tid>>2, kg = tid&3
    const int w_lrow = tid >> 2, w_kg = tid & 3;
    const int w_slot = w_kg ^ ((w_lrow >> 1) & 3);

    // wave / fragment decode
    const int wid = tid >> 6;
    const int wm = wid >> 1, wn = wid & 1;          // wave tile: rows [wm*64,+64), cols [wn*32,+32)
    const int lr = tid & 15, lq = (tid >> 4) & 3;   // lane row/col sel, k-group

    f32x4 accM[4][2], accC[4][2];
#pragma unroll
    for (int f = 0; f < 4; ++f)
#pragma unroll
        for (int g = 0; g < 2; ++g) {
            accM[f][g] = (f32x4)0.0f;
            accC[f][g] = (f32x4)0.0f;
        }

    f16x8 r_id[4];
    float r_lv[8], r_x[8];

    auto LOAD = [&](int c) {
        const int k0 = (cstart + c) * BK;
#pragma unroll
        for (int m = 0; m < 4; ++m) {
            int u = tid + 256 * m;
            int arr = u >> 9, u2 = u & 511;
            int row = u2 >> 2, kg = u2 & 3;
            const _Float16* src = (arr ? idl : idh)
                + (size_t)(ibase + row) * KPAD + k0 + kg * 8;
            r_id[m] = *reinterpret_cast<const f16x8*>(src);
        }
        {
            const int kb = k0 + w_kg * 8;
            const float* lp = lvl_hvs + (size_t)w_lrow * D + kb;
            const float* xp = x + (size_t)b * D + kb;
            if (kb + 8 <= D) {
                float4 a0 = ld4(lp), a1 = ld4(lp + 4);
                float4 b0 = ld4(xp), b1 = ld4(xp + 4);
                r_lv[0] = a0.x; r_lv[1] = a0.y; r_lv[2] = a0.z; r_lv[3] = a0.w;
                r_lv[4] = a1.x; r_lv[5] = a1.y; r_lv[6] = a1.z; r_lv[7] = a1.w;
                r_x[0] = b0.x; r_x[1] = b0.y; r_x[2] = b0.z; r_x[3] = b0.w;
                r_x[4] = b1.x; r_x[5] = b1.y; r_x[6] = b1.z; r_x[7] = b1.w;
            } else {
#pragma unroll
                for (int e = 0; e < 8; ++e) {
                    bool in = (kb + e) < D;
                    r_lv[e] = in ? lp[e] : 0.0f;
                    r_x[e]  = in ? xp[e] : 0.0f;
                }
            }
        }
    };

    auto WRITE = [&](int buf) {
#pragma unroll
        for (int m = 0; m < 4; ++m) {
            int u = tid + 256 * m;
            int arr = u >> 9, u2 = u & 511;
            int row = u2 >> 2, kg = u2 & 3;
            sA[buf][arr][row][kg ^ ((row >> 1) & 3)] = r_id[m];
        }
        {
            f16x8 h, lo;
#pragma unroll
            for (int e = 0; e < 8; ++e) {
                float w = r_x[e] * r_lv[e];
                _Float16 hh = (_Float16)w;
                h[e] = hh;
                lo[e] = (_Float16)(w - (float)hh);
            }
            sW[buf][0][w_lrow][w_slot] = h;
            sW[buf][1][w_lrow][w_slot] = lo;
        }
    };

    auto COMPUTE = [&](int buf) {
        f16x8 ah[4], al[4], bh[2], bl[2];
#pragma unroll
        for (int f = 0; f < 4; ++f) {
            int row = wm * 64 + f * 16 + lr;
            int slot = lq ^ ((row >> 1) & 3);
            ah[f] = sA[buf][0][row][slot];
            al[f] = sA[buf][1][row][slot];
        }
#pragma unroll
        for (int g = 0; g < 2; ++g) {
            int col = wn * 32 + g * 16 + lr;
            int slot = lq ^ ((col >> 1) & 3);
            bh[g] = sW[buf][0][col][slot];
            bl[g] = sW[buf][1][col][slot];
        }
#pragma unroll
        for (int f = 0; f < 4; ++f)
#pragma unroll
            for (int g = 0; g < 2; ++g) {
                accM[f][g] = __builtin_amdgcn_mfma_f32_16x16x32_f16(ah[f], bh[g], accM[f][g], 0, 0, 0);
                accC[f][g] = __builtin_amdgcn_mfma_f32_16x16x32_f16(ah[f], bl[g], accC[f][g], 0, 0, 0);
                accC[f][g] = __builtin_amdgcn_mfma_f32_16x16x32_f16(al[f], bh[g], accC[f][g], 0, 0, 0);
                accC[f][g] = __builtin_amdgcn_mfma_f32_16x16x32_f16(al[f], bl[g], accC[f][g], 0, 0, 0);
            }
    };

    LOAD(0);
    WRITE(0);
    __syncthreads();

    int cur = 0;
    for (int c = 0; c < nch; ++c) {
        const bool more = (c + 1 < nch);
        if (more) LOAD(c + 1);          // issue global loads early (T14)
        COMPUTE(cur);
        if (more) WRITE(cur ^ 1);       // write other buffer after compute
        __syncthreads();
        cur ^= 1;
    }

    // epilogue: D layout col = lane&15 (=l), row = lq*4 + reg (=i offset). main + corr in fp32.
    float* outp = part + (size_t)(s * B + b) * NI * NL;
#pragma unroll
    for (int f = 0; f < 4; ++f) {
#pragma unroll
        for (int g = 0; g < 2; ++g) {
            const int i0 = ibase + wm * 64 + f * 16 + lq * 4;
            const int l  = wn * 32 + g * 16 + lr;
#pragma unroll
            for (int r = 0; r < 4; ++r) {
                outp[(size_t)(i0 + r) * NL + l] = accM[f][g][r] + accC[f][g][r];
            }
        }
    }
}

// ---------------- Phase 2: fp64 combine + argmax (one wave per (b,i)) ----------------
__global__ __launch_bounds__(256)
void hd_phase2(const float* __restrict__ ws, float* __restrict__ out, int SS) {
    const int wid  = blockIdx.x * 4 + (threadIdx.x >> 6);   // (b,i) flat index
    const int lane = threadIdx.x & 63;                       // l
    const int b = wid >> 8, i = wid & 255;
    const float* p = ws + ((size_t)b * NI + i) * NL + lane;
    const size_t sstride = (size_t)B * NI * NL;              // 1,048,576

    double s0 = 0.0, s1 = 0.0, s2 = 0.0, s3 = 0.0;
    int ss = 0;
    for (; ss + 4 <= SS; ss += 4) {
        s0 += (double)p[(size_t)(ss + 0) * sstride];
        s1 += (double)p[(size_t)(ss + 1) * sstride];
        s2 += (double)p[(size_t)(ss + 2) * sstride];
        s3 += (double)p[(size_t)(ss + 3) * sstride];
    }
    for (; ss < SS; ++ss) s0 += (double)p[(size_t)ss * sstride];

    double mv = (s0 + s1) + (s2 + s3);
    int mi = lane;
#pragma unroll
    for (int off = 1; off < 64; off <<= 1) {
        double ov = __shfl_xor(mv, off);
        int   oi  = __shfl_xor(mi, off);
        if (ov > mv || (ov == mv && oi < mi)) { mv = ov; mi = oi; }  // first-index tie-break
    }
    if (lane == 0) out[wid] = (float)mi * BIN_LEN;
}

extern "C" void kernel_launch(void* const* d_in, const int* in_sizes, int n_in,
                              void* d_out, int out_size, void* d_ws, size_t ws_size,
                              hipStream_t stream) {
    const float* x       = (const float*)d_in[0];
    const float* id_hvs  = (const float*)d_in[1];
    const float* lvl_hvs = (const float*)d_in[2];
    float* out = (float*)d_out;

    float*     part = (float*)d_ws;
    _Float16*  idh  = (_Float16*)((char*)d_ws + OFF_IDH);
    _Float16*  idl  = idh + IDSZ;

    hd_split_id<<<dim3(NI), dim3(256), 0, stream>>>(id_hvs, idh, idl);
    hd_mfma<<<dim3(S * B * 2), dim3(256), 0, stream>>>(x, lvl_hvs, idh, idl, part);
    hd_phase2<<<dim3(B * NI / 4), dim3(256), 0, stream>>>(part, out, S);
}

// Round 7
// 90.465 us; speedup vs baseline: 64.2691x; 1.4141x over previous
//
#include <hip/hip_runtime.h>

// hd_id_lvl_decoder: scores[b,i,l] = sum_d x[b,d]*id[i,d]*lvl[l,d]; out[b,i] = argmax_l * 0.015625
// B=64, NUM_ID=256, NUM_LVL=64, D=10000.
//
// f16x2-split MFMA, 3-term (hh + hl + lh; ll dropped, ~6e-6 error, below fp32 noise):
// a = hi + lo (f16 pair), products via mfma_f32_16x16x32_f16 at ~2 PF rate.
// Phase 0: split id_hvs into f16 hi/lo arrays (zero-padded K to 10016 = 313*32) in ws.
// Phase 1: block = 128 i x {2 b's} x 64 l, 4 waves, wave tile 64x64 (f=g=4).
//          Per chunk: fold w_b = x_b*lvl in fp32, split to f16 in-reg, stage swizzled LDS,
//          3 MFMAs per (f,g) into accM (hh) + accC (hl+lh). Partials to ws.
// Phase 2: one wave per (b,i), lane = l: fp64 sum of S partials, shfl_xor argmax (first ties).

typedef _Float16 f16x8 __attribute__((ext_vector_type(8)));
typedef float f32x4 __attribute__((ext_vector_type(4)));

constexpr int D    = 10000;
constexpr int KPAD = 10016;            // 313 * 32
constexpr int B    = 64;
constexpr int NI   = 256;
constexpr int NL   = 64;
constexpr int BK   = 32;
constexpr int NCH  = KPAD / BK;        // 313 chunks
constexpr int S    = 8;                // k-splits
constexpr int BM   = 128;              // i per block
constexpr float BIN_LEN = 0.015625f;

// ws layout (bytes): [0, 32M) partials; then idh (256*10016 f16), idl.
constexpr size_t OFF_IDH = (size_t)S * B * NI * NL * 4;          // 33,554,432
constexpr size_t IDSZ    = (size_t)NI * KPAD;                     // elements per id array

__device__ __forceinline__ float4 ld4(const float* p) {
    return *reinterpret_cast<const float4*>(p);
}

// ---------------- Phase 0: split id into f16 hi/lo, zero-pad to KPAD ----------------
__global__ __launch_bounds__(256)
void hd_split_id(const float* __restrict__ id_hvs,
                 _Float16* __restrict__ idh, _Float16* __restrict__ idl) {
    const int i = blockIdx.x;          // 256 blocks, one i-row each
    for (int k = threadIdx.x; k < KPAD; k += 256) {
        float v = (k < D) ? id_hvs[(size_t)i * D + k] : 0.0f;
        _Float16 h = (_Float16)v;
        _Float16 lo = (_Float16)(v - (float)h);
        idh[(size_t)i * KPAD + k] = h;
        idl[(size_t)i * KPAD + k] = lo;
    }
}

// ---------------- Phase 1: MFMA main kernel ----------------
__global__ __launch_bounds__(256)
void hd_mfma(const float* __restrict__ x, const float* __restrict__ lvl_hvs,
             const _Float16* __restrict__ idh, const _Float16* __restrict__ idl,
             float* __restrict__ part) {
    // slot = kg ^ ((row>>1)&3) swizzle -> full-1KB-coverage permutations, conflict-free (R6: 0)
    __shared__ f16x8 sA[2][2][BM][4];       // id tiles   [buf][hi/lo][row][slot], 32 KB
    __shared__ f16x8 sW[2][2][2][NL][4];    // w tiles    [buf][hi/lo][b][row][slot], 32 KB

    const int tid = threadIdx.x;
    const int bx  = blockIdx.x;
    const int s     = bx >> 6;          // 0..S-1
    const int ibase = (bx & 1) * BM;    // 0 or 128
    const int b0    = ((bx >> 1) & 31) * 2;

    // chunk range for this split
    const int cb = NCH / S, cr = NCH % S;          // 39, 1
    const int cstart = s * cb + (s < cr ? s : cr);
    const int nch    = cb + (s < cr ? 1 : 0);

    // w staging: thread -> lvl row (tid>>2)&63, kg tid&3; handles both b's (lvl load shared)
    const int w_row = (tid >> 2) & 63, w_kg = tid & 3;
    const int w_slot = w_kg ^ ((w_row >> 1) & 3);

    // wave / fragment decode: 4 waves as 2(i) x 2(b)
    const int wid = tid >> 6;
    const int wm = wid >> 1, wn = wid & 1;          // rows [wm*64,+64), b = b0+wn
    const int lr = tid & 15, lq = (tid >> 4) & 3;   // lane row/col sel, k-group

    f32x4 accM[4][4], accC[4][4];
#pragma unroll
    for (int f = 0; f < 4; ++f)
#pragma unroll
        for (int g = 0; g < 4; ++g) {
            accM[f][g] = (f32x4)0.0f;
            accC[f][g] = (f32x4)0.0f;
        }

    f16x8 r_id[4];
    float r_lv[8], r_x0[8], r_x1[8];

    auto LOAD = [&](int c) {
        const int k0 = (cstart + c) * BK;
        // id: 4 units/thread: u = tid+256m -> arr=u>>9, row=(u&511)>>2, kg=u&3 (coalesced)
#pragma unroll
        for (int m = 0; m < 4; ++m) {
            int u = tid + 256 * m;
            int arr = u >> 9, u2 = u & 511;
            int row = u2 >> 2, kg = u2 & 3;
            const _Float16* src = (arr ? idl : idh)
                + (size_t)(ibase + row) * KPAD + k0 + kg * 8;
            r_id[m] = *reinterpret_cast<const f16x8*>(src);
        }
        {
            const int kb = k0 + w_kg * 8;
            const float* lp  = lvl_hvs + (size_t)w_row * D + kb;
            const float* xp0 = x + (size_t)b0 * D + kb;
            const float* xp1 = xp0 + D;
            if (kb + 8 <= D) {
                float4 a0 = ld4(lp),  a1 = ld4(lp + 4);
                float4 c0 = ld4(xp0), c1 = ld4(xp0 + 4);
                float4 d0 = ld4(xp1), d1 = ld4(xp1 + 4);
                r_lv[0] = a0.x; r_lv[1] = a0.y; r_lv[2] = a0.z; r_lv[3] = a0.w;
                r_lv[4] = a1.x; r_lv[5] = a1.y; r_lv[6] = a1.z; r_lv[7] = a1.w;
                r_x0[0] = c0.x; r_x0[1] = c0.y; r_x0[2] = c0.z; r_x0[3] = c0.w;
                r_x0[4] = c1.x; r_x0[5] = c1.y; r_x0[6] = c1.z; r_x0[7] = c1.w;
                r_x1[0] = d0.x; r_x1[1] = d0.y; r_x1[2] = d0.z; r_x1[3] = d0.w;
                r_x1[4] = d1.x; r_x1[5] = d1.y; r_x1[6] = d1.z; r_x1[7] = d1.w;
            } else {
#pragma unroll
                for (int e = 0; e < 8; ++e) {
                    bool in = (kb + e) < D;
                    r_lv[e] = in ? lp[e]  : 0.0f;
                    r_x0[e] = in ? xp0[e] : 0.0f;
                    r_x1[e] = in ? xp1[e] : 0.0f;
                }
            }
        }
    };

    auto WRITE = [&](int buf) {
#pragma unroll
        for (int m = 0; m < 4; ++m) {
            int u = tid + 256 * m;
            int arr = u >> 9, u2 = u & 511;
            int row = u2 >> 2, kg = u2 & 3;
            sA[buf][arr][row][kg ^ ((row >> 1) & 3)] = r_id[m];
        }
#pragma unroll
        for (int bs = 0; bs < 2; ++bs) {
            const float* rx = bs ? r_x1 : r_x0;
            f16x8 h, lo;
#pragma unroll
            for (int e = 0; e < 8; ++e) {
                float w = rx[e] * r_lv[e];
                _Float16 hh = (_Float16)w;
                h[e] = hh;
                lo[e] = (_Float16)(w - (float)hh);
            }
            sW[buf][0][bs][w_row][w_slot] = h;
            sW[buf][1][bs][w_row][w_slot] = lo;
        }
    };

    auto COMPUTE = [&](int buf) {
        f16x8 bh[4], bl[4];
#pragma unroll
        for (int g = 0; g < 4; ++g) {
            int col = g * 16 + lr;
            int slot = lq ^ ((col >> 1) & 3);
            bh[g] = sW[buf][0][wn][col][slot];
            bl[g] = sW[buf][1][wn][col][slot];
        }
#pragma unroll
        for (int f = 0; f < 4; ++f) {
            int row = wm * 64 + f * 16 + lr;
            int slot = lq ^ ((row >> 1) & 3);
            f16x8 ah = sA[buf][0][row][slot];
            f16x8 al = sA[buf][1][row][slot];
#pragma unroll
            for (int g = 0; g < 4; ++g) {
                accM[f][g] = __builtin_amdgcn_mfma_f32_16x16x32_f16(ah, bh[g], accM[f][g], 0, 0, 0);
                accC[f][g] = __builtin_amdgcn_mfma_f32_16x16x32_f16(ah, bl[g], accC[f][g], 0, 0, 0);
                accC[f][g] = __builtin_amdgcn_mfma_f32_16x16x32_f16(al, bh[g], accC[f][g], 0, 0, 0);
            }
        }
    };

    LOAD(0);
    WRITE(0);
    __syncthreads();

    int cur = 0;
    for (int c = 0; c < nch; ++c) {
        const bool more = (c + 1 < nch);
        if (more) LOAD(c + 1);          // issue global loads early (T14)
        COMPUTE(cur);
        if (more) WRITE(cur ^ 1);       // write other buffer after compute
        __syncthreads();
        cur ^= 1;
    }

    // epilogue: D layout col(lane&15)=l, row(lq*4+reg)=i offset. main + corr in fp32.
    float* outp = part + (size_t)(s * B + b0 + wn) * NI * NL;
#pragma unroll
    for (int f = 0; f < 4; ++f) {
#pragma unroll
        for (int g = 0; g < 4; ++g) {
            const int i0 = ibase + wm * 64 + f * 16 + lq * 4;
            const int l  = g * 16 + lr;
#pragma unroll
            for (int r = 0; r < 4; ++r) {
                outp[(size_t)(i0 + r) * NL + l] = accM[f][g][r] + accC[f][g][r];
            }
        }
    }
}

// ---------------- Phase 2: fp64 combine + argmax (one wave per (b,i)) ----------------
__global__ __launch_bounds__(256)
void hd_phase2(const float* __restrict__ ws, float* __restrict__ out, int SS) {
    const int wid  = blockIdx.x * 4 + (threadIdx.x >> 6);   // (b,i) flat index
    const int lane = threadIdx.x & 63;                       // l
    const int b = wid >> 8, i = wid & 255;
    const float* p = ws + ((size_t)b * NI + i) * NL + lane;
    const size_t sstride = (size_t)B * NI * NL;              // 1,048,576

    double s0 = 0.0, s1 = 0.0, s2 = 0.0, s3 = 0.0;
    int ss = 0;
    for (; ss + 4 <= SS; ss += 4) {
        s0 += (double)p[(size_t)(ss + 0) * sstride];
        s1 += (double)p[(size_t)(ss + 1) * sstride];
        s2 += (double)p[(size_t)(ss + 2) * sstride];
        s3 += (double)p[(size_t)(ss + 3) * sstride];
    }
    for (; ss < SS; ++ss) s0 += (double)p[(size_t)ss * sstride];

    double mv = (s0 + s1) + (s2 + s3);
    int mi = lane;
#pragma unroll
    for (int off = 1; off < 64; off <<= 1) {
        double ov = __shfl_xor(mv, off);
        int   oi  = __shfl_xor(mi, off);
        if (ov > mv || (ov == mv && oi < mi)) { mv = ov; mi = oi; }  // first-index tie-break
    }
    if (lane == 0) out[wid] = (float)mi * BIN_LEN;
}

extern "C" void kernel_launch(void* const* d_in, const int* in_sizes, int n_in,
                              void* d_out, int out_size, void* d_ws, size_t ws_size,
                              hipStream_t stream) {
    const float* x       = (const float*)d_in[0];
    const float* id_hvs  = (const float*)d_in[1];
    const float* lvl_hvs = (const float*)d_in[2];
    float* out = (float*)d_out;

    float*     part = (float*)d_ws;
    _Float16*  idh  = (_Float16*)((char*)d_ws + OFF_IDH);
    _Float16*  idl  = idh + IDSZ;

    hd_split_id<<<dim3(NI), dim3(256), 0, stream>>>(id_hvs, idh, idl);
    // 512 blocks: S x 32 b-pairs x 2 i-tiles
    hd_mfma<<<dim3(S * 64), dim3(256), 0, stream>>>(x, lvl_hvs, idh, idl, part);
    hd_phase2<<<dim3(B * NI / 4), dim3(256), 0, stream>>>(part, out, S);
}